// Round 6
// baseline (350.720 us; speedup 1.0000x reference)
//
#include <hip/hip_runtime.h>

// Round 6: un-fused discriminator, re-armed without hipMemsetAsync.
// r5 failed to bench ("container failed twice", no counters) — prime suspect
// is hipMemsetAsync inside kernel_launch under graph capture. Replaced with a
// plain zero-fill kernel (two ordinary launches on one stream, capture-safe).
//
// Structure:
//   1) zero_fill_kernel: 256MB contiguous 16B stores, 4 quads/thread,
//      block-chunked (block owns 1024 consecutive quads; thread k-stride is
//      256 quads = 4KB — no long power-of-2 strides). r1/r3 already proved
//      wave-uniform zero-store waves sustain fill-class BW.
//   2) scatter_canonical_kernel: one thread per INPUT quad; reads val+idx
//      (128MB linear NT streams); canonical quad -> direct 16B store into the
//      64MB of canonical positions; non-canonical -> pure atomicAdd onto the
//      pre-zeroed buffer (reference duplicate-sum; never taken on this input).
//
// Pre-registered: H_A (fused kernels were ~3TB/s-capped) -> ~280-310us win;
//                 H_B (r3 already roofline)              -> ~348-358us, revert
//                 to r3 next round and declare roofline.
//
// Geometry: H=W=256, C=256, OH=OW=512. Output quads 16,777,216; input quads
// 4,194,304. Canonical p00 of input quad tid: h*262144 + w*512 + c4*4.

typedef float  f32x4 __attribute__((ext_vector_type(4)));
typedef int    i32x4 __attribute__((ext_vector_type(4)));

__global__ __launch_bounds__(256) void zero_fill_kernel(float* __restrict__ out)
{
    // Block owns 1024 consecutive quads (16KB); each thread writes 4 quads
    // at 256-quad (4KB) stride within the block's chunk.
    f32x4* o = reinterpret_cast<f32x4*>(out);
    const f32x4 z = (f32x4)(0.f);
    const int base = blockIdx.x * 1024 + threadIdx.x;
    #pragma unroll
    for (int k = 0; k < 4; ++k)
        o[base + k * 256] = z;
}

__global__ __launch_bounds__(256) void scatter_canonical_kernel(
    const float* __restrict__ val,
    const int*   __restrict__ idx,
    float*       __restrict__ out,
    int niq)  // input quads = 4,194,304
{
    const int tid = blockIdx.x * blockDim.x + threadIdx.x;
    if (tid >= niq) return;

    const f32x4 v  = __builtin_nontemporal_load(reinterpret_cast<const f32x4*>(val) + tid);
    const i32x4 id = __builtin_nontemporal_load(reinterpret_cast<const i32x4*>(idx) + tid);

    const int c4 = tid & 63;           // channel quad (C/4 = 64)
    const int w  = (tid >> 6) & 255;   // pooled column
    const int h  = tid >> 14;          // pooled row

    // Canonical flat float offset: ((2h)*512 + 2w)*256 + 4*c4
    const int p00 = h * 262144 + w * 512 + c4 * 4;

    if (__builtin_expect(id.x == p00     && id.y == p00 + 1 &&
                         id.z == p00 + 2 && id.w == p00 + 3, 1)) {
        reinterpret_cast<f32x4*>(out)[p00 >> 2] = v;   // canonical store
    } else {
        // out already zeroed: pure scatter-add (reference duplicate-sum).
        atomicAdd(out + id.x, v.x);
        atomicAdd(out + id.y, v.y);
        atomicAdd(out + id.z, v.z);
        atomicAdd(out + id.w, v.w);
    }
}

extern "C" void kernel_launch(void* const* d_in, const int* in_sizes, int n_in,
                              void* d_out, int out_size, void* d_ws, size_t ws_size,
                              hipStream_t stream) {
    const float* val = (const float*)d_in[0];
    const int*   idx = (const int*)d_in[1];
    float* out = (float*)d_out;

    const int n   = in_sizes[0];       // 16,777,216 pooled elements
    const int nq  = n;                 // output quads (out_size/16)
    const int niq = n / 4;             // input quads

    // 1) Zero the output: 16,384 blocks × 256 threads × 4 quads = 16,777,216.
    zero_fill_kernel<<<nq / 1024, 256, 0, stream>>>(out);

    // 2) Compact canonical scatter (stream-ordered after the fill).
    const int block = 256;
    const int grid  = (niq + block - 1) / block;   // 16,384 blocks
    scatter_canonical_kernel<<<grid, block, 0, stream>>>(val, idx, out, niq);
}

// Round 7
// 336.959 us; speedup vs baseline: 1.0408x; 1.0408x over previous
//
#include <hip/hip_runtime.h>

// Round 7: REVERT to round-3 kernel (best verified: 335.3us) per the
// pre-registered outcome of the round-6 discriminator.
//
// Evidence trail:
//   r0 input-centric NT            347.1
//   r1 output-centric 1q/thread    336.3
//   r2 4q/thread 64MiB stride      356.8  (power-of-2 stride aliasing)
//   r3 = r1 + plain stores         335.3  <- this kernel
//   r4 wave-chunked 8q/thread      345.9
//   r6 split fill+scatter (448MB)  350.7  (= r3 + 15us, matching +64MB traffic
//                                          at ~6.4 TB/s + 1 extra dispatch)
// Conclusion (H_B): this kernel runs ~60us = 384MB / ~6.4 TB/s — the same
// rate the harness's own fillBufferAligned demonstrates (6.5 TB/s, 81% peak).
// The remaining ~275us of dur_us is harness reset overhead (1GiB ws poison
// ~165us + 256MB out poison ~41us + tiny reset dispatches). Traffic is at the
// op's floor: val (64MB) + idx (64MB) read once, out (256MB) written once;
// idx must be read to honor reference duplicate-sum semantics.
//
// Mapping: one thread per OUTPUT c-quad; wave lanes cover c4=0..63 of one
// (oh,ow) pixel so the role branch is wave-uniform:
//   (oh|ow) odd  -> pure zero-store wave (3/4 of waves);
//   both even    -> canonical target of pooled (h,w)=(oh/2,ow/2): load
//                   val/idx quads (linear NT streams), verify canonical
//                   indices, store v; non-canonical falls back to zero +
//                   atomicAdd (reference duplicate-sum; never taken here).
// All three streams are monotone linear sweeps. Traffic = 384MB floor.
//
// Geometry: H=W=256, C=256, OH=OW=512. NQ = 512*512*64 = 16,777,216.

typedef float  f32x4 __attribute__((ext_vector_type(4)));
typedef int    i32x4 __attribute__((ext_vector_type(4)));

__global__ __launch_bounds__(256) void unpool_oc_plainst_kernel(
    const float* __restrict__ val,
    const int*   __restrict__ idx,
    float*       __restrict__ out,
    int nq)
{
    const int tid = blockIdx.x * blockDim.x + threadIdx.x;
    if (tid >= nq) return;

    f32x4* o = reinterpret_cast<f32x4*>(out);
    const f32x4 z = (f32x4)(0.f);

    const int ow = (tid >> 6) & 511;  // output column
    const int oh = tid >> 15;         // output row

    // Wave-uniform role: all 64 lanes of a wave share (oh, ow).
    if ((oh | ow) & 1) {
        o[tid] = z;                   // plain cached streaming store
        return;
    }

    // (oh, ow) both even: canonical target of pooled pixel (h, w).
    const int c4  = tid & 63;
    const int qin = ((oh >> 1) << 14) + ((ow >> 1) << 6) + c4;
    const f32x4 v  = __builtin_nontemporal_load(reinterpret_cast<const f32x4*>(val) + qin);
    const i32x4 id = __builtin_nontemporal_load(reinterpret_cast<const i32x4*>(idx) + qin);

    const int p = tid << 2;  // expected canonical flat float index (< 2^26)
    if (__builtin_expect(id.x == p && id.y == p + 1 && id.z == p + 2 && id.w == p + 3, 1)) {
        o[tid] = v;          // canonical fast path (plain store)
    } else {
        o[tid] = z;          // zero the quad, scatter per reference semantics
        atomicAdd(out + id.x, v.x);
        atomicAdd(out + id.y, v.y);
        atomicAdd(out + id.z, v.z);
        atomicAdd(out + id.w, v.w);
    }
}

extern "C" void kernel_launch(void* const* d_in, const int* in_sizes, int n_in,
                              void* d_out, int out_size, void* d_ws, size_t ws_size,
                              hipStream_t stream) {
    const float* val = (const float*)d_in[0];
    const int*   idx = (const int*)d_in[1];
    float* out = (float*)d_out;

    const int n  = in_sizes[0];   // 16,777,216 pooled elements
    const int nq = n;             // output quads
    const int block = 256;
    const int grid  = (nq + block - 1) / block;  // 65,536 blocks
    unpool_oc_plainst_kernel<<<grid, block, 0, stream>>>(val, idx, out, nq);
}